// Round 1
// baseline (1064.126 us; speedup 1.0000x reference)
//
#include <hip/hip_runtime.h>

#define THREADS 256

__device__ __forceinline__ void atomAdd(float* p, float v) {
    unsafeAtomicAdd(p, v);  // hardware global_atomic_add_f32 on gfx950
}

// 1) in-degree histogram (self-loop added later as +1)
__global__ void k_deg(const int* __restrict__ dst, int E, float* __restrict__ deg) {
    int e = blockIdx.x * blockDim.x + threadIdx.x;
    if (e < E) atomAdd(&deg[dst[e]], 1.0f);
}

// 2) dinv[i] = rsqrt(indeg + 1)
__global__ void k_dinv(const float* __restrict__ deg, float* __restrict__ dinv, int n) {
    int i = blockIdx.x * blockDim.x + threadIdx.x;
    if (i < n) dinv[i] = rsqrtf(deg[i] + 1.0f);
}

// 3) edge pass: layer-1 scatter in 4-channel space + layer-2 src coefficient
__global__ void k_scatter(const int* __restrict__ src, const int* __restrict__ dst,
                          const float4* __restrict__ x, const float* __restrict__ dinv,
                          float* __restrict__ p1, float* __restrict__ sumd, int E) {
    int e = blockIdx.x * blockDim.x + threadIdx.x;
    if (e >= E) return;
    int s = src[e], d = dst[e];
    float ds = dinv[s], dd = dinv[d];
    float nrm = ds * dd;
    float4 xs = x[s];
    float* pd = p1 + 4 * (size_t)d;
    atomAdd(pd + 0, nrm * xs.x);
    atomAdd(pd + 1, nrm * xs.y);
    atomAdd(pd + 2, nrm * xs.z);
    atomAdd(pd + 3, nrm * xs.w);
    atomAdd(sumd + s, dd);   // layer-2: sum of dinv[dst] per src
}

// 4) per node: add self-loop, 4x64 matvec + bias + relu, weighted reduce into g[64]
//    lane c owns output channel c; each wave strides over nodes.
__global__ void k_node(const float4* __restrict__ x, const float4* __restrict__ p1,
                       const float* __restrict__ dinv, const float* __restrict__ sumd,
                       const float* __restrict__ W1, const float* __restrict__ b1,
                       float* __restrict__ g, int n) {
    int lane = threadIdx.x & 63;
    int wid = blockIdx.x * (blockDim.x >> 6) + (threadIdx.x >> 6);
    int nw = gridDim.x * (blockDim.x >> 6);
    float w0 = W1[lane], w1 = W1[64 + lane], w2 = W1[128 + lane], w3 = W1[192 + lane];
    float bb = b1[lane];
    float acc = 0.0f;
    for (int i = wid; i < n; i += nw) {
        float di = dinv[i];
        float d2 = di * di;
        float4 p = p1[i];
        float4 xi = x[i];
        float h0 = fmaf(d2, xi.x, p.x);
        float h1 = fmaf(d2, xi.y, p.y);
        float h2 = fmaf(d2, xi.z, p.z);
        float h3 = fmaf(d2, xi.w, p.w);
        float h = fmaf(h0, w0, fmaf(h1, w1, fmaf(h2, w2, fmaf(h3, w3, bb))));
        h = fmaxf(h, 0.0f);                      // relu(layer-1 output)
        float wi = fmaf(di, sumd[i], d2);        // layer-2 node weight (incl. self loop)
        acc = fmaf(wi, h, acc);
    }
    __shared__ float sacc[THREADS];
    sacc[threadIdx.x] = acc;
    __syncthreads();
    if (threadIdx.x < 64) {
        float t = sacc[threadIdx.x];
        #pragma unroll
        for (int o = 64; o < THREADS; o += 64) t += sacc[threadIdx.x + o];
        atomAdd(&g[threadIdx.x], t);
    }
}

// 5) out[j] = b2[j] + (g @ W2)[j] / n
__global__ void k_final(const float* __restrict__ g, const float* __restrict__ W2,
                        const float* __restrict__ b2, float* __restrict__ out, float inv_n) {
    int j = threadIdx.x;
    if (j < 32) {
        float a = 0.0f;
        #pragma unroll
        for (int c = 0; c < 64; ++c) a = fmaf(g[c], W2[c * 32 + j], a);
        out[j] = fmaf(a, inv_n, b2[j]);
    }
}

extern "C" void kernel_launch(void* const* d_in, const int* in_sizes, int n_in,
                              void* d_out, int out_size, void* d_ws, size_t ws_size,
                              hipStream_t stream) {
    const float* x  = (const float*)d_in[0];
    const int*   ei = (const int*)d_in[1];
    const float* W1 = (const float*)d_in[2];
    const float* b1 = (const float*)d_in[3];
    const float* W2 = (const float*)d_in[4];
    const float* b2 = (const float*)d_in[5];
    float* out = (float*)d_out;

    int n = in_sizes[0] / 4;      // 100000
    int E = in_sizes[1] / 2;      // 3200000
    const int* src = ei;
    const int* dst = ei + E;

    float* ws   = (float*)d_ws;
    float* deg  = ws;                         // n
    float* p1   = ws + (size_t)n;             // 4n (16B-aligned: n*4B = 400000)
    float* sumd = ws + 5 * (size_t)n;         // n
    float* g    = ws + 6 * (size_t)n;         // 64
    float* dinv = ws + 6 * (size_t)n + 64;    // n (fully overwritten, no zeroing)

    // zero accumulators (ws is poisoned 0xAA before every timed launch)
    hipMemsetAsync(d_ws, 0, (6 * (size_t)n + 64) * sizeof(float), stream);

    int eb = (E + THREADS - 1) / THREADS;
    int nb = (n + THREADS - 1) / THREADS;
    k_deg<<<eb, THREADS, 0, stream>>>(dst, E, deg);
    k_dinv<<<nb, THREADS, 0, stream>>>(deg, dinv, n);
    k_scatter<<<eb, THREADS, 0, stream>>>(src, dst, (const float4*)x, dinv, p1, sumd, E);
    k_node<<<256, THREADS, 0, stream>>>((const float4*)x, (const float4*)p1, dinv, sumd,
                                        W1, b1, g, n);
    k_final<<<1, 64, 0, stream>>>(g, W2, b2, out, 1.0f / (float)n);
}